// Round 5
// baseline (237.700 us; speedup 1.0000x reference)
//
#include <hip/hip_runtime.h>
#include <hip/hip_cooperative_groups.h>
#include <math.h>

namespace cg = cooperative_groups;

#define NCLS 21
#define NCO 20
#define SUB 8                  // blocks per class
#define TPB 256
#define NBLK (NCO * SUB)       // 160 blocks <= 256 CUs -> co-resident
#define RCAP 2048
#define RMAX 2000
#define SCORE_THRESH 0.05f

typedef unsigned long long u64;
typedef unsigned int u32;

// Exact equivalent of (f32_div(inter,uni) > 0.3f):  inter > IOU_MID * uni in f64.
// 0.3f = 10066330*2^-25; midpoint to next float = 20132661*2^-26. RN tie at the
// midpoint rounds to even (0.3f) -> false, matching strict ">". 25b x 24b exact in f64.
#define IOU_MID (20132661.0 / 67108864.0)

// Shared decode routine (phases C and D use the identical op sequence ->
// bitwise-identical results; matches R1-R4's absmax 0.0 formula).
__device__ __forceinline__ void decode_box(
    const float* __restrict__ rois, const float* __restrict__ loc,
    int r, int cls, float sh, float sw,
    float& by1, float& bx1, float& by2, float& bx2)
{
    float4 rb = *(const float4*)(rois + r * 4);
    float y1 = rb.x, x1 = rb.y, y2 = rb.z, x2 = rb.w;
    float h = y2 - y1, w = x2 - x1;
    float cy = y1 + 0.5f * h, cx = x1 + 0.5f * w;
    float4 l4 = *(const float4*)(loc + r * (NCLS * 4) + cls * 4);
    float dy = l4.x * 0.1f, dx = l4.y * 0.1f;
    float dh = l4.z * 0.2f, dw = l4.w * 0.2f;
    float ncy = dy * h + cy, ncx = dx * w + cx;
    float nh = expf(dh) * h, nw = expf(dw) * w;
    by1 = fminf(fmaxf(ncy - 0.5f * nh, 0.f), sh);
    bx1 = fminf(fmaxf(ncx - 0.5f * nw, 0.f), sw);
    by2 = fminf(fmaxf(ncy + 0.5f * nh, 0.f), sh);
    bx2 = fminf(fmaxf(ncx + 0.5f * nw, 0.f), sw);
}

// ---------------------------------------------------------------------------
// Cooperative kernel: 160 blocks x 256 threads, 3 grid syncs.
// ws: M u64[20][R][32] | vk u64[20][R] (unsorted keys) | ord u32[20][R]
//     (sorted-pos -> roi) | nvv int[32]
// LDS smem[4128] u64 (33 KB), phase-aliased:
//   B: skeys u64[2048] | C: 4 x f32[2048] boxes | D: flag u8[2048] + rem u64[32]@4096
// ---------------------------------------------------------------------------
__global__ __launch_bounds__(TPB) void coop_kernel(
    const float* __restrict__ loc, const float* __restrict__ scores,
    const float* __restrict__ rois, const int* __restrict__ ph,
    const int* __restrict__ pw, float* __restrict__ out, int R,
    u64* __restrict__ M, u64* __restrict__ vk, u32* __restrict__ ord,
    int* __restrict__ nvv)
{
    cg::grid_group grid = cg::this_grid();
    __shared__ u64 smem[4128];
    const int t = threadIdx.x;
    const int b = blockIdx.x;
    const int c = b >> 3;                 // class-1 index 0..19
    const int s = b & 7;                  // sub-block 0..7
    const float sh = (float)(*ph), sw = (float)(*pw);

    // ---- Phase A: per-(roi,class) softmax -> key. Invalid (p<=thresh) keys
    // are larger (smaller p -> larger ~p) so valids form a sorted prefix.
    if (b == 0 && t < 32) nvv[t] = 0;
    {
        int gt = b * TPB + t;
        if (gt < R * NCO) {
            int r = gt / NCO;
            int ccl = gt - r * NCO;       // 0..19 -> class ccl+1
            const float* srow = scores + r * NCLS;
            float m = -INFINITY;
#pragma unroll
            for (int k = 0; k < NCLS; ++k) m = fmaxf(m, srow[k]);
            float sum = 0.f, ec = 0.f;
#pragma unroll
            for (int k = 0; k < NCLS; ++k) {
                float e = expf(srow[k] - m);
                sum += e;
                if (k == ccl + 1) ec = e;
            }
            float p = ec / sum;
            vk[(size_t)ccl * R + r] =
                ((u64)(~__float_as_uint(p)) << 32) | (u32)r;
        }
    }
    grid.sync();

    // ---- Phase B: stable descending rank (== jnp.argsort(-p)) per class,
    // spread over 8 blocks; count nv via per-wave ballot + one atomic.
    {
        u64* skeys = smem;
        const u64* vkc = vk + (size_t)c * R;
        for (int k = t; k < R; k += TPB) skeys[k] = vkc[k];
        __syncthreads();
        int j = s * TPB + t;
        u64 kj = 0; bool have = (j < R); bool valid = false;
        if (have) {
            kj = skeys[j];
            valid = __uint_as_float(~(u32)(kj >> 32)) > SCORE_THRESH;
        }
        u64 bal = __ballot(valid);
        if ((t & 63) == 0 && bal) atomicAdd(&nvv[c], (int)__popcll(bal));
        if (have && valid) {              // invalid ranks >= nv, never read
            int rank = 0;
#pragma unroll 8
            for (int i = 0; i < R; ++i) rank += (skeys[i] < kj);
            ord[(size_t)c * R + rank] = (u32)j;
        }
    }
    grid.sync();

    // ---- Phase C: suppression mask build, spread over the class's 8 blocks.
    const int nv = nvv[c];
    const int nw = (nv + 63) >> 6;
    {
        float* by1 = (float*)smem;
        float* bx1 = by1 + RCAP;
        float* by2 = bx1 + RCAP;
        float* bx2 = by2 + RCAP;
        const u32* oc = ord + (size_t)c * R;
        for (int i = t; i < nv; i += TPB) {
            int r = (int)oc[i];
            float a0, a1, a2, a3;
            decode_box(rois, loc, r, c + 1, sh, sw, a0, a1, a2, a3);
            by1[i] = a0; bx1[i] = a1; by2[i] = a2; bx2[i] = a3;
        }
        __syncthreads();
        u64* Mc = M + (size_t)c * R * 32;
        int ntask = (nw * nw) << 6;       // (row-chunk ic, word v) x 64 lanes
        for (int tk = s * TPB + t; tk < ntask; tk += SUB * TPB) {
            int il = tk & 63;
            int rest = tk >> 6;
            int ic = rest / nw;
            int v = rest - ic * nw;
            if (v < ic) continue;         // strictly upper-triangular blocks
            int i = (ic << 6) + il;
            if (i >= nv) continue;
            float a1y = by1[i], a1x = bx1[i], a2y = by2[i], a2x = bx2[i];
            float iarea = (a2y - a1y) * (a2x - a1x);
            int j0 = v << 6;
            int jhi = min(64, nv - j0);
            u64 m = 0;
#pragma unroll 4
            for (int jj = 0; jj < jhi; ++jj) {
                int j = j0 + jj;
                float ty1 = fmaxf(a1y, by1[j]);
                float tx1 = fmaxf(a1x, bx1[j]);
                float ty2 = fminf(a2y, by2[j]);
                float tx2 = fminf(a2x, bx2[j]);
                float inter = fmaxf(ty2 - ty1, 0.f) * fmaxf(tx2 - tx1, 0.f);
                float jarea = (by2[j] - by1[j]) * (bx2[j] - bx1[j]);
                float uni = fmaxf(iarea + jarea - inter, 1e-10f);
                if ((double)inter > IOU_MID * (double)uni) m |= 1ull << jj;
            }
            if (v == ic) m &= (il < 63) ? (~0ull << (il + 1)) : 0ull;
            Mc[(size_t)i * 32 + v] = m;
        }
    }
    grid.sync();

    // ---- Phase D: per-class greedy resolve (wave 0 of sub-block 0) with
    // pipelined candidate prefetch + batched deferred row loads; then output.
    if (s == 0) {
        u64* remlds = smem + 4096;        // bytes 32768..33023
        if (t < 64) {
            const int lane = t;
            const u64* Mc = M + (size_t)c * R * 32;
            u64 remreg = 0;               // lane l owns removed-word l
            u64 cw_next = (nw > 0 && lane < nv && lane != 63)
                              ? Mc[(size_t)lane * 32] : 0ull;
            for (int w = 0; w < nw; ++w) {
                u64 cw = cw_next;         // M[w*64+lane][w] (lane63 forced 0)
                int inext = ((w + 1) << 6) + lane;
                cw_next = (w + 1 < nw && inext < nv && lane != 63)
                              ? Mc[(size_t)inext * 32 + (w + 1)] : 0ull;
                u64 cur = __shfl(remreg, w, 64);
                int remn = nv - (w << 6);
                u64 vb = (remn >= 64) ? ~0ull : ((1ull << remn) - 1ull);
                u64 avail = vb & ~cur;
                u64 kept = 0;
                while (avail) {           // register/shfl-only serial chain
                    int bb = __ffsll(avail) - 1;
                    kept |= 1ull << bb;
                    cur |= __shfl(cw, bb, 64);
                    avail &= ~(cur | (1ull << bb));
                }
                if (lane == w) remreg = cur;
                bool lact = (lane > w) && (lane < nw);
                u64 km = kept;
                while (km) {              // batched (8-wide) deferred ORs
                    int bs[8];
                    u64 tmp[8];
#pragma unroll
                    for (int g = 0; g < 8; ++g) {
                        bs[g] = km ? (__ffsll(km) - 1) : -1;
                        if (km) km &= km - 1;
                        tmp[g] = 0;
                    }
#pragma unroll
                    for (int g = 0; g < 8; ++g)
                        if (bs[g] >= 0 && lact)
                            tmp[g] = Mc[(size_t)((w << 6) + bs[g]) * 32 + lane];
#pragma unroll
                    for (int g = 0; g < 8; ++g) remreg |= tmp[g];
                }
            }
            if (lane < 32) remlds[lane] = (lane < nw) ? remreg : 0ull;
        }
        __syncthreads();

        unsigned char* flag = (unsigned char*)smem;   // bytes 0..2047
        for (int r = t; r < R; r += TPB) flag[r] = 0;
        __syncthreads();
        const u32* oc = ord + (size_t)c * R;
        for (int i = t; i < nv; i += TPB)
            if (!((remlds[i >> 6] >> (i & 63)) & 1ull)) flag[oc[i]] = 1;
        __syncthreads();
        float* slice = out + (size_t)c * R * 5;
        const u64* vkc = vk + (size_t)c * R;
        for (int r = t; r < R; r += TPB) {
            float v0 = 0.f, v1 = 0.f, v2 = 0.f, v3 = 0.f, v4 = 0.f;
            if (flag[r]) {
                decode_box(rois, loc, r, c + 1, sh, sw, v0, v1, v2, v3);
                v4 = __uint_as_float(~(u32)(vkc[r] >> 32));
            }
            float* p = slice + (size_t)r * 5;
            p[0] = v0; p[1] = v1; p[2] = v2; p[3] = v3; p[4] = v4;
        }
    }
}

// --------------------------- fallback: R4 fused ----------------------------
#define NTH 1024
__global__ __launch_bounds__(NTH) void fused_kernel(
    const float* __restrict__ loc, const float* __restrict__ scores,
    const float* __restrict__ rois, const int* __restrict__ ph,
    const int* __restrict__ pw, float* __restrict__ out, int R)
{
    __shared__ u64 vkey[RMAX];
    __shared__ float2 p1[RMAX], p2[RMAX];
    __shared__ u64 chunk[64 * 33];
    __shared__ u64 rem[32];
    __shared__ int cnt;

    const int t = threadIdx.x;
    const int lane = t & 63;
    const int c = blockIdx.x + 1;
    const float sh = (float)(*ph), sw = (float)(*pw);

    if (t == 0) cnt = 0;
    if (t < 32) rem[t] = 0;
    __syncthreads();

    for (int r = t; r < R; r += NTH) {
        const float* srow = scores + r * NCLS;
        float m = -INFINITY;
#pragma unroll
        for (int k = 0; k < NCLS; ++k) m = fmaxf(m, srow[k]);
        float sum = 0.f, ec = 0.f;
#pragma unroll
        for (int k = 0; k < NCLS; ++k) {
            float e = expf(srow[k] - m);
            sum += e;
            if (k == c) ec = e;
        }
        float p = ec / sum;
        if (p > SCORE_THRESH) {
            int j = atomicAdd(&cnt, 1);
            vkey[j] = ((u64)(~__float_as_uint(p)) << 32) | (u32)r;
        }
    }
    __syncthreads();
    const int nv = cnt;
    const int nw = (nv + 63) >> 6;

    u64 kk0 = 0, kk1 = 0;
    int r0 = 0, r1 = 0;
    bool in0 = (t < nv), in1 = (t + NTH < nv);
    if (in0) kk0 = vkey[t];
    if (in1) kk1 = vkey[t + NTH];
#pragma unroll 8
    for (int i = 0; i < nv; ++i) {
        u64 k = vkey[i];
        r0 += (k < kk0);
        r1 += (k < kk1);
    }
    __syncthreads();

    for (int u = 0; u < 2; ++u) {
        bool act = u ? in1 : in0;
        if (act) {
            u64 kk = u ? kk1 : kk0;
            int rank = u ? r1 : r0;
            int r = (int)(kk & 0xffffffffu);
            float b0, b1, b2, b3;
            decode_box(rois, loc, r, c, sh, sw, b0, b1, b2, b3);
            vkey[rank] = kk;
            p1[rank] = make_float2(b0, b1);
            p2[rank] = make_float2(b2, b3);
        }
    }
    __syncthreads();

    for (int w = 0; w < nw; ++w) {
        int nwr = nw - w;
        u64 remw = rem[w];
        for (int task = t; task < (nwr << 6); task += NTH) {
            int vr = task >> 6, il = task & 63;
            int i = (w << 6) + il;
            u64 m = 0;
            if (i < nv && !((remw >> il) & 1ull)) {
                int v = w + vr;
                u64 rv = rem[v];
                if (~rv != 0ull) {
                    float2 a1 = p1[i], a2 = p2[i];
                    float iarea = (a2.x - a1.x) * (a2.y - a1.y);
                    int j0 = v << 6;
                    int jhi = min(64, nv - j0);
#pragma unroll 4
                    for (int jj = 0; jj < jhi; ++jj) {
                        float2 b1 = p1[j0 + jj], b2 = p2[j0 + jj];
                        float ty1 = fmaxf(a1.x, b1.x);
                        float tx1 = fmaxf(a1.y, b1.y);
                        float ty2 = fminf(a2.x, b2.x);
                        float tx2 = fminf(a2.y, b2.y);
                        float inter = fmaxf(ty2 - ty1, 0.f) * fmaxf(tx2 - tx1, 0.f);
                        float jarea = (b2.x - b1.x) * (b2.y - b1.y);
                        float uni = fmaxf(iarea + jarea - inter, 1e-10f);
                        if ((double)inter > IOU_MID * (double)uni) m |= 1ull << jj;
                    }
                    if (vr == 0)
                        m &= (il < 63) ? (~0ull << (il + 1)) : 0ull;
                }
            }
            chunk[il * 33 + vr] = m;
        }
        __syncthreads();

        u64 cand = chunk[lane * 33];
        u64 cur = rem[w];
        int remn = nv - (w << 6);
        u64 vb = (remn >= 64) ? ~0ull : ((1ull << remn) - 1ull);
        u64 avail = vb & ~cur;
        u64 kept = 0;
        while (avail) {
            int bb = __ffsll(avail) - 1;
            kept |= 1ull << bb;
            cur |= __shfl(cand, bb, 64);
            avail &= ~(cur | (1ull << bb));
        }
        int vr = t & 31, pg = t >> 5;
        if (vr >= 1 && vr < nwr) {
            u64 acc = 0, km = kept;
            int n = 0;
            while (km) {
                int bb = __ffsll(km) - 1;
                km &= km - 1;
                if ((n & 31) == pg) acc |= chunk[bb * 33 + vr];
                ++n;
            }
            if (acc) atomicOr(&rem[w + vr], acc);
        }
        if (t == 0) rem[w] = cur;
        __syncthreads();
    }

    unsigned short* inv = (unsigned short*)chunk;
    for (int r = t; r < R; r += NTH) inv[r] = 0xffffu;
    __syncthreads();
    for (int i = t; i < nv; i += NTH)
        if (!((rem[i >> 6] >> (i & 63)) & 1ull))
            inv[(int)(vkey[i] & 0xffffffffu)] = (unsigned short)i;
    __syncthreads();
    float* slice = out + (size_t)(c - 1) * R * 5;
    for (int r = t; r < R; r += NTH) {
        int i = inv[r];
        float v0 = 0.f, v1 = 0.f, v2 = 0.f, v3 = 0.f, v4 = 0.f;
        if (i != 0xffff) {
            float2 a1 = p1[i], a2 = p2[i];
            v0 = a1.x; v1 = a1.y; v2 = a2.x; v3 = a2.y;
            v4 = __uint_as_float(~(u32)(vkey[i] >> 32));
        }
        float* p = slice + (size_t)r * 5;
        p[0] = v0; p[1] = v1; p[2] = v2; p[3] = v3; p[4] = v4;
    }
}

extern "C" void kernel_launch(void* const* d_in, const int* in_sizes, int n_in,
                              void* d_out, int out_size, void* d_ws, size_t ws_size,
                              hipStream_t stream) {
    const float* loc    = (const float*)d_in[0];   // (R, 84) f32
    const float* scores = (const float*)d_in[1];   // (R, 21) f32
    const float* rois   = (const float*)d_in[2];   // (R, 4)  f32
    const int*   ph     = (const int*)d_in[3];
    const int*   pw     = (const int*)d_in[4];
    float* out = (float*)d_out;                    // (20, R, 5) f32
    int R = in_sizes[2] / 4;

    size_t needM   = (size_t)NCO * R * 32 * 8;
    size_t needVk  = (size_t)NCO * R * 8;
    size_t needOrd = (size_t)NCO * R * 4;
    size_t need    = needM + needVk + needOrd + 128;

    if (R <= RCAP && ws_size >= need) {
        char* w  = (char*)d_ws;
        u64* M   = (u64*)w;
        u64* vk  = (u64*)(w + needM);
        u32* ordp = (u32*)(w + needM + needVk);
        int* nvv = (int*)(w + needM + needVk + needOrd);
        void* args[] = {(void*)&loc, (void*)&scores, (void*)&rois, (void*)&ph,
                        (void*)&pw, (void*)&out, (void*)&R, (void*)&M,
                        (void*)&vk, (void*)&ordp, (void*)&nvv};
        hipError_t e = hipLaunchCooperativeKernel((const void*)coop_kernel,
                                                  dim3(NBLK), dim3(TPB),
                                                  args, 0u, stream);
        if (e == hipSuccess) return;
        // else fall through to single-kernel path
    }
    if (R <= RMAX) {
        fused_kernel<<<NCO, NTH, 0, stream>>>(loc, scores, rois, ph, pw, out, R);
    }
}

// Round 7
// 183.758 us; speedup vs baseline: 1.2935x; 1.2935x over previous
//
#include <hip/hip_runtime.h>
#include <math.h>

#define NCLS 21
#define NCO 20
#define SUB 8                  // blocks per class in sort/mask kernels
#define TPB 256
#define RCAP 2048
#define RMAX 2000
#define SCORE_THRESH 0.05f

typedef unsigned long long u64;
typedef unsigned int u32;
typedef unsigned short u16;

// Exact equivalent of (f32_div(inter,uni) > 0.3f):  inter > IOU_MID * uni in f64.
// 0.3f = 10066330*2^-25; midpoint to next float = 20132661*2^-26. RN tie at the
// midpoint rounds to even (0.3f) -> false, matching strict ">". 25b x 24b exact in f64.
#define IOU_MID (20132661.0 / 67108864.0)

__device__ __forceinline__ u64 readlane64(u64 v, int l) {
    u32 lo = (u32)__builtin_amdgcn_readlane((int)(u32)v, l);
    u32 hi = (u32)__builtin_amdgcn_readlane((int)(u32)(v >> 32), l);
    return ((u64)hi << 32) | lo;
}
__device__ __forceinline__ float readlanef(float v, int l) {
    return __uint_as_float((u32)__builtin_amdgcn_readlane((int)__float_as_uint(v), l));
}

// Reference-exact box decode (absmax 0.0 through R1-R5).
__device__ __forceinline__ void decode_box(
    const float* __restrict__ rois, const float* __restrict__ loc,
    int r, int cls, float sh, float sw,
    float& by1, float& bx1, float& by2, float& bx2)
{
    float4 rb = *(const float4*)(rois + r * 4);
    float y1 = rb.x, x1 = rb.y, y2 = rb.z, x2 = rb.w;
    float h = y2 - y1, w = x2 - x1;
    float cy = y1 + 0.5f * h, cx = x1 + 0.5f * w;
    float4 l4 = *(const float4*)(loc + r * (NCLS * 4) + cls * 4);
    float dy = l4.x * 0.1f, dx = l4.y * 0.1f;
    float dh = l4.z * 0.2f, dw = l4.w * 0.2f;
    float ncy = dy * h + cy, ncx = dx * w + cx;
    float nh = expf(dh) * h, nw = expf(dw) * w;
    by1 = fminf(fmaxf(ncy - 0.5f * nh, 0.f), sh);
    bx1 = fminf(fmaxf(ncx - 0.5f * nw, 0.f), sw);
    by2 = fminf(fmaxf(ncy + 0.5f * nh, 0.f), sh);
    bx2 = fminf(fmaxf(ncx + 0.5f * nw, 0.f), sw);
}

// Reference-exact softmax prob of class cls for row r.
__device__ __forceinline__ float softmax_p(
    const float* __restrict__ scores, int r, int cls)
{
    const float* srow = scores + r * NCLS;
    float m = -INFINITY;
#pragma unroll
    for (int k = 0; k < NCLS; ++k) m = fmaxf(m, srow[k]);
    float sum = 0.f, ec = 0.f;
#pragma unroll
    for (int k = 0; k < NCLS; ++k) {
        float e = expf(srow[k] - m);
        sum += e;
        if (k == cls) ec = e;
    }
    return ec / sum;
}

// ---------------------------------------------------------------------------
// K1 sort: 160 blocks x 256. Each block recomputes all keys for its class
// (redundant x8 — avoids cross-block dependency), ranks its 256 positions via
// register/readlane compare-count, writes ord[c][rank] = key.
// key = (~p_bits)<<32 | r : ascending u64 == p desc, idx asc == jnp.argsort(-p).
// ---------------------------------------------------------------------------
__global__ __launch_bounds__(TPB) void sort_kernel(
    const float* __restrict__ scores, u64* __restrict__ ord,
    int* __restrict__ nvv, int R)
{
    __shared__ u64 skeys[RCAP];
    __shared__ int scnt;
    const int t = threadIdx.x;
    const int c = blockIdx.x >> 3;
    const int s = blockIdx.x & 7;
    if (t == 0) scnt = 0;
    __syncthreads();

    int cnt = 0;
    for (int r = t; r < R; r += TPB) {
        float p = softmax_p(scores, r, c + 1);
        cnt += (p > SCORE_THRESH);
        skeys[r] = ((u64)(~__float_as_uint(p)) << 32) | (u32)r;
    }
    for (int r = R + t; r < RCAP; r += TPB) skeys[r] = ~0ull;  // pads sort last
    atomicAdd(&scnt, cnt);
    __syncthreads();
    if (s == 0 && t == 0) nvv[c] = scnt;

    const int lane = t & 63;
    int j = s * TPB + t;               // this thread ranks position j (0..2047)
    u64 kj = skeys[j];
    int rank = 0;
    for (int u = 0; u < RCAP / 64; ++u) {
        u64 sk = skeys[(u << 6) | lane];   // one lane-strided LDS read / 64 keys
#pragma unroll 8
        for (int jj = 0; jj < 64; ++jj)
            rank += (readlane64(sk, jj) < kj);   // register broadcast, no LDS
    }
    bool valid = (j < R) && (__uint_as_float(~(u32)(kj >> 32)) > SCORE_THRESH);
    if (valid) ord[((size_t)c << 11) + rank] = kj;
}

// ---------------------------------------------------------------------------
// K2 mask: 160 blocks x 256. Sorted boxes decoded to LDS once per block;
// wave-tasks = upper-tri (row-chunk ic, word v) pairs; i-boxes per-lane,
// j-boxes broadcast via readlane -> ~17 VALU per IoU, ~no LDS inner traffic.
// Writes M[c][i][v] for v >= ic(i) (words < ic unwritten, never read).
// ---------------------------------------------------------------------------
__global__ __launch_bounds__(TPB) void mask_kernel(
    const float* __restrict__ loc, const float* __restrict__ rois,
    const int* __restrict__ ph, const int* __restrict__ pw,
    const u64* __restrict__ ord, const int* __restrict__ nvv,
    u64* __restrict__ M, int R)
{
    __shared__ float4 pb[RCAP];        // 32 KB sorted boxes
    __shared__ float ar[RCAP];         // 8 KB areas
    const int t = threadIdx.x;
    const int c = blockIdx.x >> 3;
    const int s = blockIdx.x & 7;
    const int nv = nvv[c];
    const int nw = (nv + 63) >> 6;
    const float sh = (float)(*ph), sw = (float)(*pw);

    for (int i = t; i < nv; i += TPB) {
        u64 key = ord[((size_t)c << 11) + i];
        int r = (int)(u32)key;
        float a0, a1, a2, a3;
        decode_box(rois, loc, r, c + 1, sh, sw, a0, a1, a2, a3);
        pb[i] = make_float4(a0, a1, a2, a3);
        ar[i] = (a2 - a0) * (a3 - a1);
    }
    __syncthreads();

    const int lane = t & 63;
    const int wid = (s << 2) | (t >> 6);     // 0..31 waves per class
    const int ntasks = nw * (nw + 1) / 2;
    u64* Mc = M + ((size_t)c << 16);         // c * 2048 * 32
    for (int task = wid; task < ntasks; task += SUB * 4) {
        int ic = 0, rm = task;
        while (rm >= nw - ic) { rm -= nw - ic; ++ic; }  // uniform, <=32 iters
        int v = ic + rm;
        int i = (ic << 6) + lane;
        float4 a = pb[i];                    // garbage if i>=nv (not stored)
        float iarea = ar[i];
        float4 rj = pb[(v << 6) + lane];     // j-word boxes, one per lane
        float ja_l = ar[(v << 6) + lane];
        int jcnt = min(64, nv - (v << 6));
        u64 m = 0;
        for (int jj = 0; jj < jcnt; ++jj) {
            float jy1 = readlanef(rj.x, jj);
            float jx1 = readlanef(rj.y, jj);
            float jy2 = readlanef(rj.z, jj);
            float jx2 = readlanef(rj.w, jj);
            float ja  = readlanef(ja_l, jj);
            float ty1 = fmaxf(a.x, jy1);
            float tx1 = fmaxf(a.y, jx1);
            float ty2 = fminf(a.z, jy2);
            float tx2 = fminf(a.w, jx2);
            float inter = fmaxf(ty2 - ty1, 0.f) * fmaxf(tx2 - tx1, 0.f);
            float uni = fmaxf(iarea + ja - inter, 1e-10f);
            if ((double)inter > IOU_MID * (double)uni) m |= 1ull << jj;
        }
        if (v == ic) m &= (lane < 63) ? (~0ull << (lane + 1)) : 0ull;
        if (i < nv) Mc[((size_t)i << 5) + v] = m;
    }
}

// ---------------------------------------------------------------------------
// K3 resolve: 20 blocks x 256. Wave 0: serial greedy resolve, readlane-only
// chain + 16-wide batched deferred row ORs. Waves 1-3: prefetch the class's
// mask rows into the local XCD L2 (they were written on other XCDs).
// Then all threads write the output (decode recompute for kept rows).
// ---------------------------------------------------------------------------
__global__ __launch_bounds__(TPB) void resolve_kernel(
    const float* __restrict__ loc, const float* __restrict__ rois,
    const int* __restrict__ ph, const int* __restrict__ pw,
    const u64* __restrict__ ord, const int* __restrict__ nvv,
    const u64* __restrict__ M, float* __restrict__ out, int R)
{
    __shared__ u64 remlds[34];
    __shared__ u16 inv[RCAP];
    const int t = threadIdx.x;
    const int c = blockIdx.x;
    const int nv = nvv[c];
    const int nw = (nv + 63) >> 6;
    const u64* Mc = M + ((size_t)c << 16);

    if (t >= 64) {
        // L2 warm-up: touch all live mask words (rows < nv), keep loads alive.
        u64 acc = 0;
        int total = nv << 5;
        for (int k = t - 64; k < total; k += TPB - 64) acc |= Mc[k];
        if (acc == 0x1234567887654321ull) remlds[33] = acc;  // never true
    } else {
        const int lane = t;
        u64 remreg = 0;                     // lane l owns removed-word l
        u64 cw_next = (nw > 0 && lane < nv) ? Mc[(size_t)lane << 5] : 0ull;
        for (int w = 0; w < nw; ++w) {
            u64 cw = cw_next;               // M[w*64+lane][w]
            int inx = ((w + 1) << 6) + lane;
            cw_next = (w + 1 < nw && inx < nv)
                          ? Mc[((size_t)inx << 5) + (w + 1)] : 0ull;
            u64 cur = readlane64(remreg, w);
            int remn = nv - (w << 6);
            u64 vb = (remn >= 64) ? ~0ull : ((1ull << remn) - 1ull);
            u64 avail = vb & ~cur;
            u64 kept = 0;
            while (avail) {                 // wave-uniform serial chain
                int bb = __builtin_amdgcn_readfirstlane(__ffsll(avail) - 1);
                kept |= 1ull << bb;
                cur |= readlane64(cw, bb);  // SGPR lane select guaranteed
                avail &= ~(cur | (1ull << bb));
            }
            if (lane == w) remreg = cur;
            bool lact = (lane > w) && (lane < nw);
            u64 km = kept;
            while (km) {                    // 16-wide batched deferred ORs
                int bs[16]; u64 tmp[16];
#pragma unroll
                for (int g = 0; g < 16; ++g) {
                    bs[g] = km ? (__ffsll(km) - 1) : -1;
                    if (km) km &= km - 1;
                }
#pragma unroll
                for (int g = 0; g < 16; ++g)
                    tmp[g] = (bs[g] >= 0 && lact)
                        ? Mc[((size_t)((w << 6) + bs[g]) << 5) + lane] : 0ull;
#pragma unroll
                for (int g = 0; g < 16; ++g) remreg |= tmp[g];
            }
        }
        if (lane < 32) remlds[lane] = (lane < nw) ? remreg : 0ull;
    }
    __syncthreads();

    for (int r = t; r < R; r += TPB) inv[r] = 0xffffu;
    __syncthreads();
    for (int i = t; i < nv; i += TPB)
        if (!((remlds[i >> 6] >> (i & 63)) & 1ull))
            inv[(u32)ord[((size_t)c << 11) + i]] = (u16)i;
    __syncthreads();

    const float sh = (float)(*ph), sw = (float)(*pw);
    float* slice = out + (size_t)c * R * 5;
    for (int r = t; r < R; r += TPB) {
        float v0 = 0.f, v1 = 0.f, v2 = 0.f, v3 = 0.f, v4 = 0.f;
        int i = inv[r];
        if (i != 0xffff) {
            u64 key = ord[((size_t)c << 11) + i];
            v4 = __uint_as_float(~(u32)(key >> 32));
            decode_box(rois, loc, r, c + 1, sh, sw, v0, v1, v2, v3);
        }
        float* p = slice + (size_t)r * 5;
        p[0] = v0; p[1] = v1; p[2] = v2; p[3] = v3; p[4] = v4;
    }
}

// --------------------------- fallback: R4 fused ----------------------------
#define NTH 1024
__global__ __launch_bounds__(NTH) void fused_kernel(
    const float* __restrict__ loc, const float* __restrict__ scores,
    const float* __restrict__ rois, const int* __restrict__ ph,
    const int* __restrict__ pw, float* __restrict__ out, int R)
{
    __shared__ u64 vkey[RMAX];
    __shared__ float2 p1[RMAX], p2[RMAX];
    __shared__ u64 chunk[64 * 33];
    __shared__ u64 rem[32];
    __shared__ int cnt;

    const int t = threadIdx.x;
    const int lane = t & 63;
    const int c = blockIdx.x + 1;
    const float sh = (float)(*ph), sw = (float)(*pw);

    if (t == 0) cnt = 0;
    if (t < 32) rem[t] = 0;
    __syncthreads();

    for (int r = t; r < R; r += NTH) {
        float p = softmax_p(scores, r, c);
        if (p > SCORE_THRESH) {
            int j = atomicAdd(&cnt, 1);
            vkey[j] = ((u64)(~__float_as_uint(p)) << 32) | (u32)r;
        }
    }
    __syncthreads();
    const int nv = cnt;
    const int nw = (nv + 63) >> 6;

    u64 kk0 = 0, kk1 = 0;
    int r0 = 0, r1 = 0;
    bool in0 = (t < nv), in1 = (t + NTH < nv);
    if (in0) kk0 = vkey[t];
    if (in1) kk1 = vkey[t + NTH];
#pragma unroll 8
    for (int i = 0; i < nv; ++i) {
        u64 k = vkey[i];
        r0 += (k < kk0);
        r1 += (k < kk1);
    }
    __syncthreads();

    for (int u = 0; u < 2; ++u) {
        bool act = u ? in1 : in0;
        if (act) {
            u64 kk = u ? kk1 : kk0;
            int rank = u ? r1 : r0;
            int r = (int)(kk & 0xffffffffu);
            float b0, b1, b2, b3;
            decode_box(rois, loc, r, c, sh, sw, b0, b1, b2, b3);
            vkey[rank] = kk;
            p1[rank] = make_float2(b0, b1);
            p2[rank] = make_float2(b2, b3);
        }
    }
    __syncthreads();

    for (int w = 0; w < nw; ++w) {
        int nwr = nw - w;
        u64 remw = rem[w];
        for (int task = t; task < (nwr << 6); task += NTH) {
            int vr = task >> 6, il = task & 63;
            int i = (w << 6) + il;
            u64 m = 0;
            if (i < nv && !((remw >> il) & 1ull)) {
                int v = w + vr;
                u64 rv = rem[v];
                if (~rv != 0ull) {
                    float2 a1 = p1[i], a2 = p2[i];
                    float iarea = (a2.x - a1.x) * (a2.y - a1.y);
                    int j0 = v << 6;
                    int jhi = min(64, nv - j0);
#pragma unroll 4
                    for (int jj = 0; jj < jhi; ++jj) {
                        float2 b1 = p1[j0 + jj], b2 = p2[j0 + jj];
                        float ty1 = fmaxf(a1.x, b1.x);
                        float tx1 = fmaxf(a1.y, b1.y);
                        float ty2 = fminf(a2.x, b2.x);
                        float tx2 = fminf(a2.y, b2.y);
                        float inter = fmaxf(ty2 - ty1, 0.f) * fmaxf(tx2 - tx1, 0.f);
                        float jarea = (b2.x - b1.x) * (b2.y - b1.y);
                        float uni = fmaxf(iarea + jarea - inter, 1e-10f);
                        if ((double)inter > IOU_MID * (double)uni) m |= 1ull << jj;
                    }
                    if (vr == 0)
                        m &= (il < 63) ? (~0ull << (il + 1)) : 0ull;
                }
            }
            chunk[il * 33 + vr] = m;
        }
        __syncthreads();

        u64 cand = chunk[lane * 33];
        u64 cur = rem[w];
        int remn = nv - (w << 6);
        u64 vb = (remn >= 64) ? ~0ull : ((1ull << remn) - 1ull);
        u64 avail = vb & ~cur;
        u64 kept = 0;
        while (avail) {
            int bb = __ffsll(avail) - 1;
            kept |= 1ull << bb;
            cur |= __shfl(cand, bb, 64);
            avail &= ~(cur | (1ull << bb));
        }
        int vr = t & 31, pg = t >> 5;
        if (vr >= 1 && vr < nwr) {
            u64 acc = 0, km = kept;
            int n = 0;
            while (km) {
                int bb = __ffsll(km) - 1;
                km &= km - 1;
                if ((n & 31) == pg) acc |= chunk[bb * 33 + vr];
                ++n;
            }
            if (acc) atomicOr(&rem[w + vr], acc);
        }
        if (t == 0) rem[w] = cur;
        __syncthreads();
    }

    u16* inv = (u16*)chunk;
    for (int r = t; r < R; r += NTH) inv[r] = 0xffffu;
    __syncthreads();
    for (int i = t; i < nv; i += NTH)
        if (!((rem[i >> 6] >> (i & 63)) & 1ull))
            inv[(int)(vkey[i] & 0xffffffffu)] = (u16)i;
    __syncthreads();
    float* slice = out + (size_t)(c - 1) * R * 5;
    for (int r = t; r < R; r += NTH) {
        int i = inv[r];
        float v0 = 0.f, v1 = 0.f, v2 = 0.f, v3 = 0.f, v4 = 0.f;
        if (i != 0xffff) {
            float2 a1 = p1[i], a2 = p2[i];
            v0 = a1.x; v1 = a1.y; v2 = a2.x; v3 = a2.y;
            v4 = __uint_as_float(~(u32)(vkey[i] >> 32));
        }
        float* p = slice + (size_t)r * 5;
        p[0] = v0; p[1] = v1; p[2] = v2; p[3] = v3; p[4] = v4;
    }
}

extern "C" void kernel_launch(void* const* d_in, const int* in_sizes, int n_in,
                              void* d_out, int out_size, void* d_ws, size_t ws_size,
                              hipStream_t stream) {
    const float* loc    = (const float*)d_in[0];   // (R, 84) f32
    const float* scores = (const float*)d_in[1];   // (R, 21) f32
    const float* rois   = (const float*)d_in[2];   // (R, 4)  f32
    const int*   ph     = (const int*)d_in[3];
    const int*   pw     = (const int*)d_in[4];
    float* out = (float*)d_out;                    // (20, R, 5) f32
    int R = in_sizes[2] / 4;

    // ws: M u64[20][2048][32] | ord u64[20][2048] | nvv int[32]
    size_t needM   = (size_t)NCO * RCAP * 32 * 8;  // 10.5 MB
    size_t needOrd = (size_t)NCO * RCAP * 8;       // 328 KB
    size_t need    = needM + needOrd + 128;

    if (R <= RCAP && ws_size >= need) {
        char* w  = (char*)d_ws;
        u64* M   = (u64*)w;
        u64* ordp = (u64*)(w + needM);
        int* nvv = (int*)(w + needM + needOrd);
        sort_kernel<<<NCO * SUB, TPB, 0, stream>>>(scores, ordp, nvv, R);
        mask_kernel<<<NCO * SUB, TPB, 0, stream>>>(loc, rois, ph, pw, ordp, nvv,
                                                   M, R);
        resolve_kernel<<<NCO, TPB, 0, stream>>>(loc, rois, ph, pw, ordp, nvv,
                                                M, out, R);
    } else if (R <= RMAX) {
        fused_kernel<<<NCO, NTH, 0, stream>>>(loc, scores, rois, ph, pw, out, R);
    }
}

// Round 9
// 166.323 us; speedup vs baseline: 1.4291x; 1.1048x over previous
//
#include <hip/hip_runtime.h>
#include <math.h>

#define NCLS 21
#define NCO 20
#define SUB 8                  // blocks per class in mask kernel
#define TPB 256
#define RCAP 2048
#define RMAX 2000
#define SCORE_THRESH 0.05f

typedef unsigned long long u64;
typedef unsigned int u32;
typedef unsigned short u16;

// Exact equivalent of (f32_div(inter,uni) > 0.3f):  inter > IOU_MID * uni in f64.
// 0.3f = 10066330*2^-25; midpoint to next float = 20132661*2^-26. RN tie at the
// midpoint rounds to even (0.3f) -> false, matching strict ">". 25b x 24b exact in f64.
#define IOU_MID (20132661.0 / 67108864.0)

__device__ __forceinline__ u64 readlane64(u64 v, int l) {
    u32 lo = (u32)__builtin_amdgcn_readlane((int)(u32)v, l);
    u32 hi = (u32)__builtin_amdgcn_readlane((int)(u32)(v >> 32), l);
    return ((u64)hi << 32) | lo;
}
__device__ __forceinline__ float readlanef(float v, int l) {
    return __uint_as_float((u32)__builtin_amdgcn_readlane((int)__float_as_uint(v), l));
}

// Reference-exact box decode (absmax 0.0 through R1-R7).
__device__ __forceinline__ void decode_box(
    const float* __restrict__ rois, const float* __restrict__ loc,
    int r, int cls, float sh, float sw,
    float& by1, float& bx1, float& by2, float& bx2)
{
    float4 rb = *(const float4*)(rois + r * 4);
    float y1 = rb.x, x1 = rb.y, y2 = rb.z, x2 = rb.w;
    float h = y2 - y1, w = x2 - x1;
    float cy = y1 + 0.5f * h, cx = x1 + 0.5f * w;
    float4 l4 = *(const float4*)(loc + r * (NCLS * 4) + cls * 4);
    float dy = l4.x * 0.1f, dx = l4.y * 0.1f;
    float dh = l4.z * 0.2f, dw = l4.w * 0.2f;
    float ncy = dy * h + cy, ncx = dx * w + cx;
    float nh = expf(dh) * h, nw = expf(dw) * w;
    by1 = fminf(fmaxf(ncy - 0.5f * nh, 0.f), sh);
    bx1 = fminf(fmaxf(ncx - 0.5f * nw, 0.f), sw);
    by2 = fminf(fmaxf(ncy + 0.5f * nh, 0.f), sh);
    bx2 = fminf(fmaxf(ncx + 0.5f * nw, 0.f), sw);
}

// Reference-exact softmax prob of class cls for row r.
__device__ __forceinline__ float softmax_p(
    const float* __restrict__ scores, int r, int cls)
{
    const float* srow = scores + r * NCLS;
    float m = -INFINITY;
#pragma unroll
    for (int k = 0; k < NCLS; ++k) m = fmaxf(m, srow[k]);
    float sum = 0.f, ec = 0.f;
#pragma unroll
    for (int k = 0; k < NCLS; ++k) {
        float e = expf(srow[k] - m);
        sum += e;
        if (k == cls) ec = e;
    }
    return ec / sum;
}

// ---------------------------------------------------------------------------
// K1 sort: 20 blocks x 1024 (one class per block). Softmax + valid-only
// compaction (unordered — rank is determined by the full key, so result is
// deterministic), pad to x64 with ~0ull, then rank nv keys against nv keys
// via lane-strided LDS load + readlane broadcast.
// CRITICAL (R8 crash): the ranking loop must have a UNIFORM trip count — every
// lane must execute the vkey load whose register is readlane-broadcast;
// only the store is guarded. Partially-active waves otherwise broadcast
// garbage registers (readlane ignores EXEC) -> OOB ord writes -> fault.
// key = (~p_bits)<<32 | r : ascending u64 == p desc, idx asc == jnp.argsort(-p).
// ---------------------------------------------------------------------------
#define STH 1024
__global__ __launch_bounds__(STH) void sort_kernel(
    const float* __restrict__ scores, u64* __restrict__ ord,
    int* __restrict__ nvv, int R)
{
    __shared__ u64 vkey[RCAP];
    __shared__ int cnt;
    const int t = threadIdx.x;
    const int c = blockIdx.x;          // class-1 index 0..19
    if (t == 0) cnt = 0;
    __syncthreads();

    for (int r = t; r < R; r += STH) {
        float p = softmax_p(scores, r, c + 1);
        if (p > SCORE_THRESH) {
            int j = atomicAdd(&cnt, 1);
            vkey[j] = ((u64)(~__float_as_uint(p)) << 32) | (u32)r;
        }
    }
    __syncthreads();
    const int nv = cnt;
    const int nv64 = (nv + 63) & ~63;
    for (int i = nv + t; i < nv64; i += STH) vkey[i] = ~0ull;  // never counts
    if (t == 0) nvv[c] = nv;
    __syncthreads();

    const int lane = t & 63;
    for (int ibase = 0; ibase < nv; ibase += STH) {   // uniform trip count
        int i = ibase + t;
        bool act = (i < nv);
        u64 kj = act ? vkey[i] : ~0ull;
        int rank = 0;
        for (int u = 0; u < nv64; u += 64) {
            u64 sk = vkey[u | lane];       // executed by ALL lanes
#pragma unroll 16
            for (int jj = 0; jj < 64; ++jj)
                rank += (readlane64(sk, jj) < kj);   // register broadcast
        }
        if (act) ord[((size_t)c << 11) + rank] = kj;
    }
}

// ---------------------------------------------------------------------------
// K2 mask: 160 blocks x 256. Sorted boxes decoded to LDS once per block;
// wave-tasks = upper-tri (row-chunk ic, word v) pairs; i-boxes per-lane,
// j-boxes broadcast via readlane -> ~17 VALU per IoU, ~no LDS inner traffic.
// Writes M[c][i][v] for v >= ic(i) (words < ic unwritten, never read).
// All readlane broadcasts are from loads executed unconditionally by the
// whole wave (task loop trip count is wave-uniform).
// ---------------------------------------------------------------------------
__global__ __launch_bounds__(TPB) void mask_kernel(
    const float* __restrict__ loc, const float* __restrict__ rois,
    const int* __restrict__ ph, const int* __restrict__ pw,
    const u64* __restrict__ ord, const int* __restrict__ nvv,
    u64* __restrict__ M, int R)
{
    __shared__ float4 pb[RCAP];        // 32 KB sorted boxes
    __shared__ float ar[RCAP];         // 8 KB areas
    const int t = threadIdx.x;
    const int c = blockIdx.x >> 3;
    const int s = blockIdx.x & 7;
    const int nv = nvv[c];
    const int nw = (nv + 63) >> 6;
    const float sh = (float)(*ph), sw = (float)(*pw);

    for (int i = t; i < nv; i += TPB) {
        u64 key = ord[((size_t)c << 11) + i];
        int r = (int)(u32)key;
        float a0, a1, a2, a3;
        decode_box(rois, loc, r, c + 1, sh, sw, a0, a1, a2, a3);
        pb[i] = make_float4(a0, a1, a2, a3);
        ar[i] = (a2 - a0) * (a3 - a1);
    }
    __syncthreads();

    const int lane = t & 63;
    const int wid = (s << 2) | (t >> 6);     // 0..31 waves per class
    const int ntasks = nw * (nw + 1) / 2;
    u64* Mc = M + ((size_t)c << 16);         // c * 2048 * 32
    for (int task = wid; task < ntasks; task += SUB * 4) {
        int ic = 0, rm = task;
        while (rm >= nw - ic) { rm -= nw - ic; ++ic; }  // uniform, <=32 iters
        int v = ic + rm;
        int i = (ic << 6) + lane;
        float4 a = pb[i];                    // garbage if i>=nv (not stored)
        float iarea = ar[i];
        float4 rj = pb[(v << 6) + lane];     // j-word boxes, one per lane
        float ja_l = ar[(v << 6) + lane];
        int jcnt = min(64, nv - (v << 6));
        u64 m = 0;
        for (int jj = 0; jj < jcnt; ++jj) {
            float jy1 = readlanef(rj.x, jj);
            float jx1 = readlanef(rj.y, jj);
            float jy2 = readlanef(rj.z, jj);
            float jx2 = readlanef(rj.w, jj);
            float ja  = readlanef(ja_l, jj);
            float ty1 = fmaxf(a.x, jy1);
            float tx1 = fmaxf(a.y, jx1);
            float ty2 = fminf(a.z, jy2);
            float tx2 = fminf(a.w, jx2);
            float inter = fmaxf(ty2 - ty1, 0.f) * fmaxf(tx2 - tx1, 0.f);
            float uni = fmaxf(iarea + ja - inter, 1e-10f);
            if ((double)inter > IOU_MID * (double)uni) m |= 1ull << jj;
        }
        if (v == ic) m &= (lane < 63) ? (~0ull << (lane + 1)) : 0ull;
        if (i < nv) Mc[((size_t)i << 5) + v] = m;
    }
}

// ---------------------------------------------------------------------------
// K3 resolve: 20 blocks x 256. Wave 0: serial greedy resolve, readlane-only
// chain + 16-wide batched deferred row ORs (whole wave always active inside
// the t<64 branch -> readlane is safe). Waves 1-3: prefetch the class's mask
// rows into the local XCD L2. Then all threads write the output.
// ---------------------------------------------------------------------------
__global__ __launch_bounds__(TPB) void resolve_kernel(
    const float* __restrict__ loc, const float* __restrict__ rois,
    const int* __restrict__ ph, const int* __restrict__ pw,
    const u64* __restrict__ ord, const int* __restrict__ nvv,
    const u64* __restrict__ M, float* __restrict__ out, int R)
{
    __shared__ u64 remlds[34];
    __shared__ u16 inv[RCAP];
    const int t = threadIdx.x;
    const int c = blockIdx.x;
    const int nv = nvv[c];
    const int nw = (nv + 63) >> 6;
    const u64* Mc = M + ((size_t)c << 16);

    if (t >= 64) {
        // L2 warm-up: touch all live mask words (rows < nv), keep loads alive.
        u64 acc = 0;
        int total = nv << 5;
        for (int k = t - 64; k < total; k += TPB - 64) acc |= Mc[k];
        if (acc == 0x1234567887654321ull) remlds[33] = acc;  // never true
    } else {
        const int lane = t;
        u64 remreg = 0;                     // lane l owns removed-word l
        u64 cw_next = (nw > 0 && lane < nv) ? Mc[(size_t)lane << 5] : 0ull;
        for (int w = 0; w < nw; ++w) {
            u64 cw = cw_next;               // M[w*64+lane][w]
            int inx = ((w + 1) << 6) + lane;
            cw_next = (w + 1 < nw && inx < nv)
                          ? Mc[((size_t)inx << 5) + (w + 1)] : 0ull;
            u64 cur = readlane64(remreg, w);
            int remn = nv - (w << 6);
            u64 vb = (remn >= 64) ? ~0ull : ((1ull << remn) - 1ull);
            u64 avail = vb & ~cur;
            u64 kept = 0;
            while (avail) {                 // wave-uniform serial chain
                int bb = __builtin_amdgcn_readfirstlane(__ffsll(avail) - 1);
                kept |= 1ull << bb;
                cur |= readlane64(cw, bb);  // SGPR lane select guaranteed
                avail &= ~(cur | (1ull << bb));
            }
            if (lane == w) remreg = cur;
            bool lact = (lane > w) && (lane < nw);
            u64 km = kept;
            while (km) {                    // 16-wide batched deferred ORs
                int bs[16]; u64 tmp[16];
#pragma unroll
                for (int g = 0; g < 16; ++g) {
                    bs[g] = km ? (__ffsll(km) - 1) : -1;
                    if (km) km &= km - 1;
                }
#pragma unroll
                for (int g = 0; g < 16; ++g)
                    tmp[g] = (bs[g] >= 0 && lact)
                        ? Mc[((size_t)((w << 6) + bs[g]) << 5) + lane] : 0ull;
#pragma unroll
                for (int g = 0; g < 16; ++g) remreg |= tmp[g];
            }
        }
        if (lane < 32) remlds[lane] = (lane < nw) ? remreg : 0ull;
    }
    __syncthreads();

    for (int r = t; r < R; r += TPB) inv[r] = 0xffffu;
    __syncthreads();
    for (int i = t; i < nv; i += TPB)
        if (!((remlds[i >> 6] >> (i & 63)) & 1ull))
            inv[(u32)ord[((size_t)c << 11) + i]] = (u16)i;
    __syncthreads();

    const float sh = (float)(*ph), sw = (float)(*pw);
    float* slice = out + (size_t)c * R * 5;
    for (int r = t; r < R; r += TPB) {
        float v0 = 0.f, v1 = 0.f, v2 = 0.f, v3 = 0.f, v4 = 0.f;
        int i = inv[r];
        if (i != 0xffff) {
            u64 key = ord[((size_t)c << 11) + i];
            v4 = __uint_as_float(~(u32)(key >> 32));
            decode_box(rois, loc, r, c + 1, sh, sw, v0, v1, v2, v3);
        }
        float* p = slice + (size_t)r * 5;
        p[0] = v0; p[1] = v1; p[2] = v2; p[3] = v3; p[4] = v4;
    }
}

// --------------------------- fallback: R4 fused ----------------------------
#define NTH 1024
__global__ __launch_bounds__(NTH) void fused_kernel(
    const float* __restrict__ loc, const float* __restrict__ scores,
    const float* __restrict__ rois, const int* __restrict__ ph,
    const int* __restrict__ pw, float* __restrict__ out, int R)
{
    __shared__ u64 vkey[RMAX];
    __shared__ float2 p1[RMAX], p2[RMAX];
    __shared__ u64 chunk[64 * 33];
    __shared__ u64 rem[32];
    __shared__ int cnt;

    const int t = threadIdx.x;
    const int lane = t & 63;
    const int c = blockIdx.x + 1;
    const float sh = (float)(*ph), sw = (float)(*pw);

    if (t == 0) cnt = 0;
    if (t < 32) rem[t] = 0;
    __syncthreads();

    for (int r = t; r < R; r += NTH) {
        float p = softmax_p(scores, r, c);
        if (p > SCORE_THRESH) {
            int j = atomicAdd(&cnt, 1);
            vkey[j] = ((u64)(~__float_as_uint(p)) << 32) | (u32)r;
        }
    }
    __syncthreads();
    const int nv = cnt;
    const int nw = (nv + 63) >> 6;

    u64 kk0 = 0, kk1 = 0;
    int r0 = 0, r1 = 0;
    bool in0 = (t < nv), in1 = (t + NTH < nv);
    if (in0) kk0 = vkey[t];
    if (in1) kk1 = vkey[t + NTH];
#pragma unroll 8
    for (int i = 0; i < nv; ++i) {
        u64 k = vkey[i];
        r0 += (k < kk0);
        r1 += (k < kk1);
    }
    __syncthreads();

    for (int u = 0; u < 2; ++u) {
        bool act = u ? in1 : in0;
        if (act) {
            u64 kk = u ? kk1 : kk0;
            int rank = u ? r1 : r0;
            int r = (int)(kk & 0xffffffffu);
            float b0, b1, b2, b3;
            decode_box(rois, loc, r, c, sh, sw, b0, b1, b2, b3);
            vkey[rank] = kk;
            p1[rank] = make_float2(b0, b1);
            p2[rank] = make_float2(b2, b3);
        }
    }
    __syncthreads();

    for (int w = 0; w < nw; ++w) {
        int nwr = nw - w;
        u64 remw = rem[w];
        for (int task = t; task < (nwr << 6); task += NTH) {
            int vr = task >> 6, il = task & 63;
            int i = (w << 6) + il;
            u64 m = 0;
            if (i < nv && !((remw >> il) & 1ull)) {
                int v = w + vr;
                u64 rv = rem[v];
                if (~rv != 0ull) {
                    float2 a1 = p1[i], a2 = p2[i];
                    float iarea = (a2.x - a1.x) * (a2.y - a1.y);
                    int j0 = v << 6;
                    int jhi = min(64, nv - j0);
#pragma unroll 4
                    for (int jj = 0; jj < jhi; ++jj) {
                        float2 b1 = p1[j0 + jj], b2 = p2[j0 + jj];
                        float ty1 = fmaxf(a1.x, b1.x);
                        float tx1 = fmaxf(a1.y, b1.y);
                        float ty2 = fminf(a2.x, b2.x);
                        float tx2 = fminf(a2.y, b2.y);
                        float inter = fmaxf(ty2 - ty1, 0.f) * fmaxf(tx2 - tx1, 0.f);
                        float jarea = (b2.x - b1.x) * (b2.y - b1.y);
                        float uni = fmaxf(iarea + jarea - inter, 1e-10f);
                        if ((double)inter > IOU_MID * (double)uni) m |= 1ull << jj;
                    }
                    if (vr == 0)
                        m &= (il < 63) ? (~0ull << (il + 1)) : 0ull;
                }
            }
            chunk[il * 33 + vr] = m;
        }
        __syncthreads();

        u64 cand = chunk[lane * 33];
        u64 cur = rem[w];
        int remn = nv - (w << 6);
        u64 vb = (remn >= 64) ? ~0ull : ((1ull << remn) - 1ull);
        u64 avail = vb & ~cur;
        u64 kept = 0;
        while (avail) {
            int bb = __ffsll(avail) - 1;
            kept |= 1ull << bb;
            cur |= __shfl(cand, bb, 64);
            avail &= ~(cur | (1ull << bb));
        }
        int vr = t & 31, pg = t >> 5;
        if (vr >= 1 && vr < nwr) {
            u64 acc = 0, km = kept;
            int n = 0;
            while (km) {
                int bb = __ffsll(km) - 1;
                km &= km - 1;
                if ((n & 31) == pg) acc |= chunk[bb * 33 + vr];
                ++n;
            }
            if (acc) atomicOr(&rem[w + vr], acc);
        }
        if (t == 0) rem[w] = cur;
        __syncthreads();
    }

    u16* inv = (u16*)chunk;
    for (int r = t; r < R; r += NTH) inv[r] = 0xffffu;
    __syncthreads();
    for (int i = t; i < nv; i += NTH)
        if (!((rem[i >> 6] >> (i & 63)) & 1ull))
            inv[(int)(vkey[i] & 0xffffffffu)] = (u16)i;
    __syncthreads();
    float* slice = out + (size_t)(c - 1) * R * 5;
    for (int r = t; r < R; r += NTH) {
        int i = inv[r];
        float v0 = 0.f, v1 = 0.f, v2 = 0.f, v3 = 0.f, v4 = 0.f;
        if (i != 0xffff) {
            float2 a1 = p1[i], a2 = p2[i];
            v0 = a1.x; v1 = a1.y; v2 = a2.x; v3 = a2.y;
            v4 = __uint_as_float(~(u32)(vkey[i] >> 32));
        }
        float* p = slice + (size_t)r * 5;
        p[0] = v0; p[1] = v1; p[2] = v2; p[3] = v3; p[4] = v4;
    }
}

extern "C" void kernel_launch(void* const* d_in, const int* in_sizes, int n_in,
                              void* d_out, int out_size, void* d_ws, size_t ws_size,
                              hipStream_t stream) {
    const float* loc    = (const float*)d_in[0];   // (R, 84) f32
    const float* scores = (const float*)d_in[1];   // (R, 21) f32
    const float* rois   = (const float*)d_in[2];   // (R, 4)  f32
    const int*   ph     = (const int*)d_in[3];
    const int*   pw     = (const int*)d_in[4];
    float* out = (float*)d_out;                    // (20, R, 5) f32
    int R = in_sizes[2] / 4;

    // ws: M u64[20][2048][32] | ord u64[20][2048] | nvv int[32]
    size_t needM   = (size_t)NCO * RCAP * 32 * 8;  // 10.5 MB
    size_t needOrd = (size_t)NCO * RCAP * 8;       // 328 KB
    size_t need    = needM + needOrd + 128;

    if (R <= RCAP && ws_size >= need) {
        char* w  = (char*)d_ws;
        u64* M   = (u64*)w;
        u64* ordp = (u64*)(w + needM);
        int* nvv = (int*)(w + needM + needOrd);
        sort_kernel<<<NCO, STH, 0, stream>>>(scores, ordp, nvv, R);
        mask_kernel<<<NCO * SUB, TPB, 0, stream>>>(loc, rois, ph, pw, ordp, nvv,
                                                   M, R);
        resolve_kernel<<<NCO, TPB, 0, stream>>>(loc, rois, ph, pw, ordp, nvv,
                                                M, out, R);
    } else if (R <= RMAX) {
        fused_kernel<<<NCO, NTH, 0, stream>>>(loc, scores, rois, ph, pw, out, R);
    }
}